// Round 4
// baseline (181.841 us; speedup 1.0000x reference)
//
#include <hip/hip_runtime.h>

typedef unsigned short u16;
typedef __attribute__((ext_vector_type(8))) short bf16x8;
typedef __attribute__((ext_vector_type(4))) float f32x4;

#define NB 4
#define NT 1024
#define NC 768
#define NH 12
#define HD 64

__device__ __forceinline__ u16 f2bf(float f) {
  union { float f; unsigned u; } v; v.f = f;
  unsigned r = v.u + 0x7FFFu + ((v.u >> 16) & 1u);
  return (u16)(r >> 16);
}
__device__ __forceinline__ float bf2f(u16 h) {
  union { unsigned u; float f; } v; v.u = ((unsigned)h) << 16;
  return v.f;
}

__device__ __forceinline__ void gld16(const u16* g, u16* l) {
  __builtin_amdgcn_global_load_lds((const __attribute__((address_space(1))) void*)g,
                                   (__attribute__((address_space(3))) void*)l, 16, 0, 0);
}

// ---------------- fused prep: conv_x | conv_w | fire_bias ----------------
// blocks [0,12288): x->bf16 ; [12288,12864): weight transpose ; [12864,13888): fire table
__global__ __launch_bounds__(256) void prep_k(const float* __restrict__ x,
                                              const float* __restrict__ Wq,
                                              const float* __restrict__ Wk,
                                              const float* __restrict__ Wv,
                                              const float* __restrict__ Wp,
                                              const float* __restrict__ w1,
                                              const float* __restrict__ b1,
                                              const float* __restrict__ w2,
                                              const float* __restrict__ b2,
                                              const float* __restrict__ cP,
                                              const float* __restrict__ LmP,
                                              u16* __restrict__ xb,
                                              u16* __restrict__ Wt,
                                              u16* __restrict__ Wtp,
                                              float* __restrict__ bias) {
  __shared__ u16 tile[64][65];
  const int bid = blockIdx.x;
  const int tid = threadIdx.x;
  if (bid < 12288) {
    int i = bid * 256 + tid;
    xb[i] = f2bf(x[i]);
  } else if (bid < 12864) {
    int idx = bid - 12288;
    int z = idx / 144, rem = idx - z * 144;
    int k0 = (rem / 12) * 64, n0 = (rem % 12) * 64;
    const float* src = (z == 0) ? Wq : (z == 1) ? Wk : (z == 2) ? Wv : Wp;
    const int c = tid & 63, r4 = tid >> 6;
#pragma unroll
    for (int p = 0; p < 16; ++p) {
      int kk = p * 4 + r4;
      tile[kk][c] = f2bf(src[(size_t)(k0 + kk) * NC + n0 + c]);
    }
    __syncthreads();
    u16* dst = (z < 3) ? (Wt + (size_t)z * NC * NC) : Wtp;
#pragma unroll
    for (int p = 0; p < 16; ++p) {
      int nn = p * 4 + r4;
      dst[(size_t)(n0 + nn) * NC + k0 + c] = tile[c][nn];
    }
  } else {
    int q = bid - 12864;
    float c = cP[0], Lm = LmP[0];
    float thresh = fabsf(Lm * 512.0f);
    float pn = fmaxf((float)q, thresh);
    float inv_nl = 1.0f / (logf(fabsf(c * pn) + 1.0f) + 1e-6f);
    for (int rel = tid; rel < 257; rel += 256) {
      float z = logf(fabsf(c * (float)rel) + 1.0f) * inv_nl;
      float acc[NH];
#pragma unroll
      for (int hh = 0; hh < NH; ++hh) acc[hh] = b2[hh];
#pragma unroll
      for (int j = 0; j < 32; ++j) {
        float hj = fmaxf(z * w1[j] + b1[j], 0.0f);
#pragma unroll
        for (int hh = 0; hh < NH; ++hh) acc[hh] += hj * w2[j * NH + hh];
      }
#pragma unroll
      for (int hh = 0; hh < NH; ++hh)
        bias[((size_t)hh * NT + q) * 257 + rel] = acc[hh];
    }
  }
}

// ---------------- GEMM (m97 structure): A[M][K] bf16, Bt[N][K] bf16 ----------------
template <bool F32OUT, int WR, int WC, int AI, int BJ>
__global__ __launch_bounds__(256, 4) void gemm_lds(const u16* __restrict__ A,
                                                   const u16* __restrict__ Bt,
                                                   void* __restrict__ Cv,
                                                   int M, int N, int K) {
  constexpr int BM = WR * AI * 16;
  constexpr int BN = WC * BJ * 16;
  __shared__ u16 As[BM * 32];
  __shared__ u16 Bs[BN * 32];
  const int tid = threadIdx.x;
  const int wid = tid >> 6, lane = tid & 63;
  const int wr = wid / WC, wc = wid % WC;
  const int m0 = blockIdx.x * BM, n0 = blockIdx.y * BN;
  const int lr = lane & 15, lk = (lane >> 4) << 3;
  const int srow = wid * 16 + (lane >> 2);
  const int scol = (lane & 3) * 8;
  f32x4 acc[AI][BJ] = {};
  const u16* Ag = A + (size_t)(m0 + srow) * K + scol;
  const u16* Bg = Bt + (size_t)(n0 + srow) * K + scol;
  u16* Al = &As[(wid * 16) * 32];
  u16* Bl = &Bs[(wid * 16) * 32];

  for (int k0 = 0; k0 < K; k0 += 32) {
#pragma unroll
    for (int ia = 0; ia < BM / 64; ++ia)
      gld16(Ag + (size_t)(ia * 64) * K + k0, Al + ia * 64 * 32);
#pragma unroll
    for (int ib = 0; ib < BN / 64; ++ib)
      gld16(Bg + (size_t)(ib * 64) * K + k0, Bl + ib * 64 * 32);
    __syncthreads();
    bf16x8 af[AI], bfv[BJ];
#pragma unroll
    for (int i = 0; i < AI; ++i)
      af[i] = *(const bf16x8*)&As[(wr * AI * 16 + i * 16 + lr) * 32 + lk];
#pragma unroll
    for (int j = 0; j < BJ; ++j)
      bfv[j] = *(const bf16x8*)&Bs[(wc * BJ * 16 + j * 16 + lr) * 32 + lk];
#pragma unroll
    for (int i = 0; i < AI; ++i)
#pragma unroll
      for (int j = 0; j < BJ; ++j)
        acc[i][j] = __builtin_amdgcn_mfma_f32_16x16x32_bf16(af[i], bfv[j], acc[i][j], 0, 0, 0);
    __syncthreads();
  }
  const int rbase = (lane >> 4) * 4;
#pragma unroll
  for (int i = 0; i < AI; ++i)
#pragma unroll
    for (int j = 0; j < BJ; ++j)
#pragma unroll
      for (int r = 0; r < 4; ++r) {
        size_t row = m0 + wr * AI * 16 + i * 16 + rbase + r;
        size_t col = n0 + wc * BJ * 16 + j * 16 + lr;
        if (F32OUT)
          ((float*)Cv)[row * N + col] = acc[i][j][r];
        else
          ((u16*)Cv)[row * N + col] = f2bf(acc[i][j][r]);
      }
}

// ---------------- RoPE + head split with LDS transpose for V ----------------
__global__ __launch_bounds__(256) void rope_split_k(const u16* __restrict__ qkv,
                                                    u16* __restrict__ Q,
                                                    u16* __restrict__ K,
                                                    u16* __restrict__ Vt) {
  __shared__ u16 vlds[64][65];
  const int bh = blockIdx.x;
  const int t0 = blockIdx.y * 64;
  const int b = bh / NH, h = bh - b * NH;
  const int tid = threadIdx.x;
  const int d = tid & 63;
  const int i = d & 31;
  const size_t base = ((size_t)bh << 16);
  float inv = __expf(-(float)i * (0.03125f * 9.2103403719761836f));
#pragma unroll
  for (int p = 0; p < 16; ++p) {
    int tl = p * 4 + (tid >> 6);
    int t = t0 + tl;
    size_t row = (size_t)(b * NT + t) * 2304 + h * HD;
    float ang = (float)t * inv;
    float s, c;
    __sincosf(ang, &s, &c);
    float qa = bf2f(qkv[row + i]);
    float qb = bf2f(qkv[row + i + 32]);
    float ka = bf2f(qkv[row + 768 + i]);
    float kb = bf2f(qkv[row + 768 + i + 32]);
    float qv = (d < 32) ? (qa * c - qb * s) : (qa * s + qb * c);
    float kv = (d < 32) ? (ka * c - kb * s) : (ka * s + kb * c);
    Q[base + (size_t)t * HD + d] = f2bf(qv);
    K[base + (size_t)t * HD + d] = f2bf(kv);
    vlds[tl][d] = qkv[row + 1536 + d];
  }
  __syncthreads();
#pragma unroll
  for (int p = 0; p < 16; ++p) {
    int dd = p * 4 + (tid >> 6);
    int tl = tid & 63;
    Vt[base + (size_t)dd * NT + t0 + tl] = vlds[tl][dd];
  }
}

// ---------------- windowed flash attention, split-K across wave pairs ----------------
// grid (48, 32); 4 waves/block = 2 pairs; pair handles one q-tile (16 queries),
// roles split the key-window chunks; online-softmax merge via LDS.
__global__ __launch_bounds__(256, 6) void attn_k(const u16* __restrict__ Q,
                                                 const u16* __restrict__ K,
                                                 const u16* __restrict__ Vt,
                                                 const float* __restrict__ bias,
                                                 u16* __restrict__ Y) {
  __shared__ __align__(16) u16 plds[4][16][72];
  __shared__ __align__(16) float mbuf[2][64][24];
  const int bh = blockIdx.x;
  const int b = bh / NH, h = bh - b * NH;
  const int wid = threadIdx.x >> 6, lane = threadIdx.x & 63;
  const int pair = wid >> 1, role = wid & 1;
  const int qt = blockIdx.y * 2 + pair;
  const int q0 = qt << 4;
  const int lr = lane & 15, lg = lane >> 4, lk = lg << 3;
  const u16* Qb = Q + ((size_t)bh << 16);
  const u16* Kb = K + ((size_t)bh << 16);
  const u16* Vb = Vt + ((size_t)bh << 16);
  const float* biash = bias + (size_t)h * NT * 257;

  bf16x8 aq0 = *(const bf16x8*)(Qb + (q0 + lr) * HD + lk);
  bf16x8 aq1 = *(const bf16x8*)(Qb + (q0 + lr) * HD + 32 + lk);
  f32x4 yacc[4] = {};
  float mrun[4] = {-1e30f, -1e30f, -1e30f, -1e30f};
  float lrun[4] = {0.f, 0.f, 0.f, 0.f};
  u16(*pl)[72] = plds[wid];

  int cstart = q0 - 256;
  if (cstart < 0) cstart = 0;
  cstart &= ~63;
  const int nchunks = ((q0 + 15) - cstart) / 64 + 1;
  const int nA = nchunks >> 1;
  const int i0 = role ? nA : 0;
  const int i1 = role ? nchunks : nA;

  for (int ci = i0; ci < i1; ++ci) {
    const int c = cstart + ci * 64;
    bf16x8 bk[4][2], bv[4][2];
#pragma unroll
    for (int kk = 0; kk < 4; ++kk) {
      const u16* kp = Kb + (size_t)(c + kk * 16 + lr) * HD + lk;
      bk[kk][0] = *(const bf16x8*)kp;
      bk[kk][1] = *(const bf16x8*)(kp + 32);
    }
#pragma unroll
    for (int dt = 0; dt < 4; ++dt) {
      const u16* vp = Vb + (size_t)(dt * 16 + lr) * NT + c + lk;
      bv[dt][0] = *(const bf16x8*)vp;
      bv[dt][1] = *(const bf16x8*)(vp + 32);
    }
    float sv[4][4];
#pragma unroll
    for (int kk = 0; kk < 4; ++kk) {
      f32x4 t = {};
      t = __builtin_amdgcn_mfma_f32_16x16x32_bf16(aq0, bk[kk][0], t, 0, 0, 0);
      t = __builtin_amdgcn_mfma_f32_16x16x32_bf16(aq1, bk[kk][1], t, 0, 0, 0);
      const int kcol = c + kk * 16 + lr;
#pragma unroll
      for (int r = 0; r < 4; ++r) {
        int qrow = q0 + lg * 4 + r;
        int rel = qrow - kcol;
        sv[kk][r] = (rel >= 0 && rel <= 256)
                        ? t[r] * 0.125f + biash[(size_t)qrow * 257 + rel]
                        : -1e30f;
      }
    }
    float scale[4];
#pragma unroll
    for (int r = 0; r < 4; ++r) {
      float m = fmaxf(fmaxf(sv[0][r], sv[1][r]), fmaxf(sv[2][r], sv[3][r]));
#pragma unroll
      for (int off = 1; off < 16; off <<= 1)
        m = fmaxf(m, __shfl_xor(m, off, 64));
      float mn = fmaxf(mrun[r], m);
      scale[r] = __expf(mrun[r] - mn);
      mrun[r] = mn;
      float ss = 0.f;
#pragma unroll
      for (int kk = 0; kk < 4; ++kk) {
        float p = __expf(sv[kk][r] - mn);
        sv[kk][r] = p;
        ss += p;
      }
#pragma unroll
      for (int off = 1; off < 16; off <<= 1)
        ss += __shfl_xor(ss, off, 64);
      lrun[r] = lrun[r] * scale[r] + ss;
    }
#pragma unroll
    for (int dt = 0; dt < 4; ++dt)
#pragma unroll
      for (int r = 0; r < 4; ++r) yacc[dt][r] *= scale[r];
#pragma unroll
    for (int kk = 0; kk < 4; ++kk)
#pragma unroll
      for (int r = 0; r < 4; ++r)
        pl[lg * 4 + r][kk * 16 + lr] = f2bf(sv[kk][r]);
    asm volatile("s_waitcnt lgkmcnt(0)" ::: "memory");
    bf16x8 ap0 = *(const bf16x8*)&pl[lr][lk];
    bf16x8 ap1 = *(const bf16x8*)&pl[lr][32 + lk];
#pragma unroll
    for (int dt = 0; dt < 4; ++dt) {
      yacc[dt] = __builtin_amdgcn_mfma_f32_16x16x32_bf16(ap0, bv[dt][0], yacc[dt], 0, 0, 0);
      yacc[dt] = __builtin_amdgcn_mfma_f32_16x16x32_bf16(ap1, bv[dt][1], yacc[dt], 0, 0, 0);
    }
  }

  // ---- split-K merge: role 1 publishes, role 0 combines + writes ----
  if (role == 1) {
    float* mb = &mbuf[pair][lane][0];
#pragma unroll
    for (int dt = 0; dt < 4; ++dt) *(f32x4*)(mb + dt * 4) = yacc[dt];
#pragma unroll
    for (int r = 0; r < 4; ++r) { mb[16 + r] = mrun[r]; mb[20 + r] = lrun[r]; }
  }
  __syncthreads();
  if (role == 0) {
    const float* mb = &mbuf[pair][lane][0];
    float sA[4], sB[4];
#pragma unroll
    for (int r = 0; r < 4; ++r) {
      float mB = mb[16 + r], lB = mb[20 + r];
      float mx = fmaxf(mrun[r], mB);
      float eA = __expf(mrun[r] - mx), eB = __expf(mB - mx);
      float linv = 1.0f / (lrun[r] * eA + lB * eB);
      sA[r] = eA * linv;
      sB[r] = eB * linv;
    }
#pragma unroll
    for (int dt = 0; dt < 4; ++dt) {
      f32x4 yB = *(const f32x4*)(mb + dt * 4);
#pragma unroll
      for (int r = 0; r < 4; ++r) {
        int qrow = q0 + lg * 4 + r;
        int d = dt * 16 + lr;
        float val = yacc[dt][r] * sA[r] + yB[r] * sB[r];
        Y[(size_t)(b * NT + qrow) * NC + h * HD + d] = f2bf(val);
      }
    }
  }
}

// ---------------- workspace layout ----------------
static constexpr size_t OFF_XB = 0;
static constexpr size_t OFF_WT = OFF_XB + 6291456;
static constexpr size_t OFF_WTP = OFF_WT + 3538944;
static constexpr size_t OFF_QKV = OFF_WTP + 1179648;
static constexpr size_t OFF_Q = OFF_QKV + 18874368;
static constexpr size_t OFF_K = OFF_Q + 6291456;
static constexpr size_t OFF_VT = OFF_K + 6291456;
static constexpr size_t OFF_BIAS = OFF_VT + 6291456;
static constexpr size_t OFF_Y = OFF_BIAS + 12632064;

extern "C" void kernel_launch(void* const* d_in, const int* in_sizes, int n_in,
                              void* d_out, int out_size, void* d_ws, size_t ws_size,
                              hipStream_t stream) {
  const float* x = (const float*)d_in[0];
  const float* Wq = (const float*)d_in[1];
  const float* Wk = (const float*)d_in[2];
  const float* Wv = (const float*)d_in[3];
  const float* Wp = (const float*)d_in[4];
  const float* fw1 = (const float*)d_in[5];
  const float* fb1 = (const float*)d_in[6];
  const float* fw2 = (const float*)d_in[7];
  const float* fb2 = (const float*)d_in[8];
  const float* fc = (const float*)d_in[9];
  const float* fLm = (const float*)d_in[10];

  char* ws = (char*)d_ws;
  u16* xb = (u16*)(ws + OFF_XB);
  u16* Wt = (u16*)(ws + OFF_WT);
  u16* Wtp = (u16*)(ws + OFF_WTP);
  u16* qkv = (u16*)(ws + OFF_QKV);
  u16* Qb = (u16*)(ws + OFF_Q);
  u16* Kb = (u16*)(ws + OFF_K);
  u16* Vtb = (u16*)(ws + OFF_VT);
  float* biasb = (float*)(ws + OFF_BIAS);
  u16* Yb = (u16*)(ws + OFF_Y);

  prep_k<<<13888, 256, 0, stream>>>(x, Wq, Wk, Wv, Wp, fw1, fb1, fw2, fb2, fc, fLm,
                                    xb, Wt, Wtp, biasb);
  gemm_lds<false, 2, 2, 4, 4><<<dim3(32, 18), 256, 0, stream>>>(xb, Wt, qkv, 4096, 2304, 768);
  rope_split_k<<<dim3(48, 16), 256, 0, stream>>>(qkv, Qb, Kb, Vtb);
  attn_k<<<dim3(48, 32), 256, 0, stream>>>(Qb, Kb, Vtb, biasb, Yb);
  gemm_lds<true, 1, 4, 4, 2><<<dim3(64, 6), 256, 0, stream>>>(Yb, Wtp, d_out, 4096, 768, 768);
}

// Round 5
// 133.880 us; speedup vs baseline: 1.3582x; 1.3582x over previous
//
#include <hip/hip_runtime.h>

typedef unsigned short u16;
typedef __attribute__((ext_vector_type(8))) short bf16x8;
typedef __attribute__((ext_vector_type(4))) float f32x4;

#define NB 4
#define NT 1024
#define NC 768
#define NH 12
#define HD 64

__device__ __forceinline__ u16 f2bf(float f) {
  union { float f; unsigned u; } v; v.f = f;
  unsigned r = v.u + 0x7FFFu + ((v.u >> 16) & 1u);
  return (u16)(r >> 16);
}
__device__ __forceinline__ float bf2f(u16 h) {
  union { unsigned u; float f; } v; v.u = ((unsigned)h) << 16;
  return v.f;
}

__device__ __forceinline__ void gld16(const u16* g, u16* l) {
  __builtin_amdgcn_global_load_lds((const __attribute__((address_space(1))) void*)g,
                                   (__attribute__((address_space(3))) void*)l, 16, 0, 0);
}

// ---------------- fused prep: conv_x | conv_w | fire_bias ----------------
__global__ __launch_bounds__(256) void prep_k(const float* __restrict__ x,
                                              const float* __restrict__ Wq,
                                              const float* __restrict__ Wk,
                                              const float* __restrict__ Wv,
                                              const float* __restrict__ Wp,
                                              const float* __restrict__ w1,
                                              const float* __restrict__ b1,
                                              const float* __restrict__ w2,
                                              const float* __restrict__ b2,
                                              const float* __restrict__ cP,
                                              const float* __restrict__ LmP,
                                              u16* __restrict__ xb,
                                              u16* __restrict__ Wt,
                                              u16* __restrict__ Wtp,
                                              float* __restrict__ bias) {
  __shared__ u16 tile[64][65];
  const int bid = blockIdx.x;
  const int tid = threadIdx.x;
  if (bid < 12288) {
    int i = bid * 256 + tid;
    xb[i] = f2bf(x[i]);
  } else if (bid < 12864) {
    int idx = bid - 12288;
    int z = idx / 144, rem = idx - z * 144;
    int k0 = (rem / 12) * 64, n0 = (rem % 12) * 64;
    const float* src = (z == 0) ? Wq : (z == 1) ? Wk : (z == 2) ? Wv : Wp;
    const int c = tid & 63, r4 = tid >> 6;
#pragma unroll
    for (int p = 0; p < 16; ++p) {
      int kk = p * 4 + r4;
      tile[kk][c] = f2bf(src[(size_t)(k0 + kk) * NC + n0 + c]);
    }
    __syncthreads();
    u16* dst = (z < 3) ? (Wt + (size_t)z * NC * NC) : Wtp;
#pragma unroll
    for (int p = 0; p < 16; ++p) {
      int nn = p * 4 + r4;
      dst[(size_t)(n0 + nn) * NC + k0 + c] = tile[c][nn];
    }
  } else {
    int q = bid - 12864;
    float c = cP[0], Lm = LmP[0];
    float thresh = fabsf(Lm * 512.0f);
    float pn = fmaxf((float)q, thresh);
    float inv_nl = 1.0f / (logf(fabsf(c * pn) + 1.0f) + 1e-6f);
    for (int rel = tid; rel < 257; rel += 256) {
      float z = logf(fabsf(c * (float)rel) + 1.0f) * inv_nl;
      float acc[NH];
#pragma unroll
      for (int hh = 0; hh < NH; ++hh) acc[hh] = b2[hh];
#pragma unroll
      for (int j = 0; j < 32; ++j) {
        float hj = fmaxf(z * w1[j] + b1[j], 0.0f);
#pragma unroll
        for (int hh = 0; hh < NH; ++hh) acc[hh] += hj * w2[j * NH + hh];
      }
#pragma unroll
      for (int hh = 0; hh < NH; ++hh)
        bias[((size_t)hh * NT + q) * 257 + rel] = acc[hh];
    }
  }
}

// ---------------- GEMM (m97 structure): A[M][K] bf16, Bt[N][K] bf16 ----------------
template <bool F32OUT, int WR, int WC, int AI, int BJ>
__global__ __launch_bounds__(256, 4) void gemm_lds(const u16* __restrict__ A,
                                                   const u16* __restrict__ Bt,
                                                   void* __restrict__ Cv,
                                                   int M, int N, int K) {
  constexpr int BM = WR * AI * 16;
  constexpr int BN = WC * BJ * 16;
  __shared__ u16 As[BM * 32];
  __shared__ u16 Bs[BN * 32];
  const int tid = threadIdx.x;
  const int wid = tid >> 6, lane = tid & 63;
  const int wr = wid / WC, wc = wid % WC;
  const int m0 = blockIdx.x * BM, n0 = blockIdx.y * BN;
  const int lr = lane & 15, lk = (lane >> 4) << 3;
  const int srow = wid * 16 + (lane >> 2);
  const int scol = (lane & 3) * 8;
  f32x4 acc[AI][BJ] = {};
  const u16* Ag = A + (size_t)(m0 + srow) * K + scol;
  const u16* Bg = Bt + (size_t)(n0 + srow) * K + scol;
  u16* Al = &As[(wid * 16) * 32];
  u16* Bl = &Bs[(wid * 16) * 32];

  for (int k0 = 0; k0 < K; k0 += 32) {
#pragma unroll
    for (int ia = 0; ia < BM / 64; ++ia)
      gld16(Ag + (size_t)(ia * 64) * K + k0, Al + ia * 64 * 32);
#pragma unroll
    for (int ib = 0; ib < BN / 64; ++ib)
      gld16(Bg + (size_t)(ib * 64) * K + k0, Bl + ib * 64 * 32);
    __syncthreads();
    bf16x8 af[AI], bfv[BJ];
#pragma unroll
    for (int i = 0; i < AI; ++i)
      af[i] = *(const bf16x8*)&As[(wr * AI * 16 + i * 16 + lr) * 32 + lk];
#pragma unroll
    for (int j = 0; j < BJ; ++j)
      bfv[j] = *(const bf16x8*)&Bs[(wc * BJ * 16 + j * 16 + lr) * 32 + lk];
#pragma unroll
    for (int i = 0; i < AI; ++i)
#pragma unroll
      for (int j = 0; j < BJ; ++j)
        acc[i][j] = __builtin_amdgcn_mfma_f32_16x16x32_bf16(af[i], bfv[j], acc[i][j], 0, 0, 0);
    __syncthreads();
  }
  const int rbase = (lane >> 4) * 4;
#pragma unroll
  for (int i = 0; i < AI; ++i)
#pragma unroll
    for (int j = 0; j < BJ; ++j)
#pragma unroll
      for (int r = 0; r < 4; ++r) {
        size_t row = m0 + wr * AI * 16 + i * 16 + rbase + r;
        size_t col = n0 + wc * BJ * 16 + j * 16 + lr;
        if (F32OUT)
          ((float*)Cv)[row * N + col] = acc[i][j][r];
        else
          ((u16*)Cv)[row * N + col] = f2bf(acc[i][j][r]);
      }
}

// ---------------- RoPE + head split with LDS transpose for V ----------------
__global__ __launch_bounds__(256) void rope_split_k(const u16* __restrict__ qkv,
                                                    u16* __restrict__ Q,
                                                    u16* __restrict__ K,
                                                    u16* __restrict__ Vt) {
  __shared__ u16 vlds[64][65];
  const int bh = blockIdx.x;
  const int t0 = blockIdx.y * 64;
  const int b = bh / NH, h = bh - b * NH;
  const int tid = threadIdx.x;
  const int d = tid & 63;
  const int i = d & 31;
  const size_t base = ((size_t)bh << 16);
  float inv = __expf(-(float)i * (0.03125f * 9.2103403719761836f));
#pragma unroll
  for (int p = 0; p < 16; ++p) {
    int tl = p * 4 + (tid >> 6);
    int t = t0 + tl;
    size_t row = (size_t)(b * NT + t) * 2304 + h * HD;
    float ang = (float)t * inv;
    float s, c;
    __sincosf(ang, &s, &c);
    float qa = bf2f(qkv[row + i]);
    float qb = bf2f(qkv[row + i + 32]);
    float ka = bf2f(qkv[row + 768 + i]);
    float kb = bf2f(qkv[row + 768 + i + 32]);
    float qv = (d < 32) ? (qa * c - qb * s) : (qa * s + qb * c);
    float kv = (d < 32) ? (ka * c - kb * s) : (ka * s + kb * c);
    Q[base + (size_t)t * HD + d] = f2bf(qv);
    K[base + (size_t)t * HD + d] = f2bf(kv);
    vlds[tl][d] = qkv[row + 1536 + d];
  }
  __syncthreads();
#pragma unroll
  for (int p = 0; p < 16; ++p) {
    int dd = p * 4 + (tid >> 6);
    int tl = tid & 63;
    Vt[base + (size_t)dd * NT + t0 + tl] = vlds[tl][dd];
  }
}

// ---------------- windowed flash attention, split-K across wave pairs ----------------
// grid (48, 32); 4 waves/block = 2 pairs; pair handles one q-tile (16 queries),
// roles split the key-window chunks; online-softmax merge via LDS.
// launch_bounds (256,4): VGPR cap 128 >= natural ~85 usage (round-3 loop was 72);
// the (256,6)=cap-85->40 experiment spilled 180MB/dispatch to scratch.
__global__ __launch_bounds__(256, 4) void attn_k(const u16* __restrict__ Q,
                                                 const u16* __restrict__ K,
                                                 const u16* __restrict__ Vt,
                                                 const float* __restrict__ bias,
                                                 u16* __restrict__ Y) {
  __shared__ __align__(16) u16 plds[4][16][72];
  __shared__ __align__(16) float mbuf[2][64][24];
  const int bh = blockIdx.x;
  const int b = bh / NH, h = bh - b * NH;
  const int wid = threadIdx.x >> 6, lane = threadIdx.x & 63;
  const int pair = wid >> 1, role = wid & 1;
  const int qt = blockIdx.y * 2 + pair;
  const int q0 = qt << 4;
  const int lr = lane & 15, lg = lane >> 4, lk = lg << 3;
  const u16* Qb = Q + ((size_t)bh << 16);
  const u16* Kb = K + ((size_t)bh << 16);
  const u16* Vb = Vt + ((size_t)bh << 16);
  const float* biash = bias + (size_t)h * NT * 257;

  bf16x8 aq0 = *(const bf16x8*)(Qb + (q0 + lr) * HD + lk);
  bf16x8 aq1 = *(const bf16x8*)(Qb + (q0 + lr) * HD + 32 + lk);
  f32x4 yacc[4] = {};
  float mrun[4] = {-1e30f, -1e30f, -1e30f, -1e30f};
  float lrun[4] = {0.f, 0.f, 0.f, 0.f};
  u16(*pl)[72] = plds[wid];

  int cstart = q0 - 256;
  if (cstart < 0) cstart = 0;
  cstart &= ~63;
  const int nchunks = ((q0 + 15) - cstart) / 64 + 1;
  const int nA = nchunks >> 1;
  const int i0 = role ? nA : 0;
  const int i1 = role ? nchunks : nA;

  for (int ci = i0; ci < i1; ++ci) {
    const int c = cstart + ci * 64;
    bf16x8 bk[4][2], bv[4][2];
#pragma unroll
    for (int kk = 0; kk < 4; ++kk) {
      const u16* kp = Kb + (size_t)(c + kk * 16 + lr) * HD + lk;
      bk[kk][0] = *(const bf16x8*)kp;
      bk[kk][1] = *(const bf16x8*)(kp + 32);
    }
#pragma unroll
    for (int dt = 0; dt < 4; ++dt) {
      const u16* vp = Vb + (size_t)(dt * 16 + lr) * NT + c + lk;
      bv[dt][0] = *(const bf16x8*)vp;
      bv[dt][1] = *(const bf16x8*)(vp + 32);
    }
    float sv[4][4];
#pragma unroll
    for (int kk = 0; kk < 4; ++kk) {
      f32x4 t = {};
      t = __builtin_amdgcn_mfma_f32_16x16x32_bf16(aq0, bk[kk][0], t, 0, 0, 0);
      t = __builtin_amdgcn_mfma_f32_16x16x32_bf16(aq1, bk[kk][1], t, 0, 0, 0);
      const int kcol = c + kk * 16 + lr;
#pragma unroll
      for (int r = 0; r < 4; ++r) {
        int qrow = q0 + lg * 4 + r;
        int rel = qrow - kcol;
        sv[kk][r] = (rel >= 0 && rel <= 256)
                        ? t[r] * 0.125f + biash[(size_t)qrow * 257 + rel]
                        : -1e30f;
      }
    }
    float scale[4];
#pragma unroll
    for (int r = 0; r < 4; ++r) {
      float m = fmaxf(fmaxf(sv[0][r], sv[1][r]), fmaxf(sv[2][r], sv[3][r]));
#pragma unroll
      for (int off = 1; off < 16; off <<= 1)
        m = fmaxf(m, __shfl_xor(m, off, 64));
      float mn = fmaxf(mrun[r], m);
      scale[r] = __expf(mrun[r] - mn);
      mrun[r] = mn;
      float ss = 0.f;
#pragma unroll
      for (int kk = 0; kk < 4; ++kk) {
        float p = __expf(sv[kk][r] - mn);
        sv[kk][r] = p;
        ss += p;
      }
#pragma unroll
      for (int off = 1; off < 16; off <<= 1)
        ss += __shfl_xor(ss, off, 64);
      lrun[r] = lrun[r] * scale[r] + ss;
    }
#pragma unroll
    for (int dt = 0; dt < 4; ++dt)
#pragma unroll
      for (int r = 0; r < 4; ++r) yacc[dt][r] *= scale[r];
#pragma unroll
    for (int kk = 0; kk < 4; ++kk)
#pragma unroll
      for (int r = 0; r < 4; ++r)
        pl[lg * 4 + r][kk * 16 + lr] = f2bf(sv[kk][r]);
    asm volatile("s_waitcnt lgkmcnt(0)" ::: "memory");
    bf16x8 ap0 = *(const bf16x8*)&pl[lr][lk];
    bf16x8 ap1 = *(const bf16x8*)&pl[lr][32 + lk];
#pragma unroll
    for (int dt = 0; dt < 4; ++dt) {
      yacc[dt] = __builtin_amdgcn_mfma_f32_16x16x32_bf16(ap0, bv[dt][0], yacc[dt], 0, 0, 0);
      yacc[dt] = __builtin_amdgcn_mfma_f32_16x16x32_bf16(ap1, bv[dt][1], yacc[dt], 0, 0, 0);
    }
  }

  // ---- split-K merge: role 1 publishes, role 0 combines + writes ----
  if (role == 1) {
    float* mb = &mbuf[pair][lane][0];
#pragma unroll
    for (int dt = 0; dt < 4; ++dt) *(f32x4*)(mb + dt * 4) = yacc[dt];
#pragma unroll
    for (int r = 0; r < 4; ++r) { mb[16 + r] = mrun[r]; mb[20 + r] = lrun[r]; }
  }
  __syncthreads();
  if (role == 0) {
    const float* mb = &mbuf[pair][lane][0];
    float sA[4], sB[4];
#pragma unroll
    for (int r = 0; r < 4; ++r) {
      float mB = mb[16 + r], lB = mb[20 + r];
      float mx = fmaxf(mrun[r], mB);
      float eA = __expf(mrun[r] - mx), eB = __expf(mB - mx);
      float linv = 1.0f / (lrun[r] * eA + lB * eB);
      sA[r] = eA * linv;
      sB[r] = eB * linv;
    }
#pragma unroll
    for (int dt = 0; dt < 4; ++dt) {
      f32x4 yB = *(const f32x4*)(mb + dt * 4);
#pragma unroll
      for (int r = 0; r < 4; ++r) {
        int qrow = q0 + lg * 4 + r;
        int d = dt * 16 + lr;
        float val = yacc[dt][r] * sA[r] + yB[r] * sB[r];
        Y[(size_t)(b * NT + qrow) * NC + h * HD + d] = f2bf(val);
      }
    }
  }
}

// ---------------- workspace layout ----------------
static constexpr size_t OFF_XB = 0;
static constexpr size_t OFF_WT = OFF_XB + 6291456;
static constexpr size_t OFF_WTP = OFF_WT + 3538944;
static constexpr size_t OFF_QKV = OFF_WTP + 1179648;
static constexpr size_t OFF_Q = OFF_QKV + 18874368;
static constexpr size_t OFF_K = OFF_Q + 6291456;
static constexpr size_t OFF_VT = OFF_K + 6291456;
static constexpr size_t OFF_BIAS = OFF_VT + 6291456;
static constexpr size_t OFF_Y = OFF_BIAS + 12632064;

extern "C" void kernel_launch(void* const* d_in, const int* in_sizes, int n_in,
                              void* d_out, int out_size, void* d_ws, size_t ws_size,
                              hipStream_t stream) {
  const float* x = (const float*)d_in[0];
  const float* Wq = (const float*)d_in[1];
  const float* Wk = (const float*)d_in[2];
  const float* Wv = (const float*)d_in[3];
  const float* Wp = (const float*)d_in[4];
  const float* fw1 = (const float*)d_in[5];
  const float* fb1 = (const float*)d_in[6];
  const float* fw2 = (const float*)d_in[7];
  const float* fb2 = (const float*)d_in[8];
  const float* fc = (const float*)d_in[9];
  const float* fLm = (const float*)d_in[10];

  char* ws = (char*)d_ws;
  u16* xb = (u16*)(ws + OFF_XB);
  u16* Wt = (u16*)(ws + OFF_WT);
  u16* Wtp = (u16*)(ws + OFF_WTP);
  u16* qkv = (u16*)(ws + OFF_QKV);
  u16* Qb = (u16*)(ws + OFF_Q);
  u16* Kb = (u16*)(ws + OFF_K);
  u16* Vtb = (u16*)(ws + OFF_VT);
  float* biasb = (float*)(ws + OFF_BIAS);
  u16* Yb = (u16*)(ws + OFF_Y);

  prep_k<<<13888, 256, 0, stream>>>(x, Wq, Wk, Wv, Wp, fw1, fb1, fw2, fb2, fc, fLm,
                                    xb, Wt, Wtp, biasb);
  gemm_lds<false, 2, 2, 4, 4><<<dim3(32, 18), 256, 0, stream>>>(xb, Wt, qkv, 4096, 2304, 768);
  rope_split_k<<<dim3(48, 16), 256, 0, stream>>>(qkv, Qb, Kb, Vtb);
  attn_k<<<dim3(48, 32), 256, 0, stream>>>(Qb, Kb, Vtb, biasb, Yb);
  gemm_lds<true, 1, 4, 4, 2><<<dim3(64, 6), 256, 0, stream>>>(Yb, Wtp, d_out, 4096, 768, 768);
}

// Round 6
// 108.751 us; speedup vs baseline: 1.6721x; 1.2311x over previous
//
#include <hip/hip_runtime.h>

typedef unsigned short u16;
typedef __attribute__((ext_vector_type(8))) short bf16x8;
typedef __attribute__((ext_vector_type(4))) float f32x4;

#define NB 4
#define NT 1024
#define NC 768
#define NH 12
#define HD 64

__device__ __forceinline__ u16 f2bf(float f) {
  union { float f; unsigned u; } v; v.f = f;
  unsigned r = v.u + 0x7FFFu + ((v.u >> 16) & 1u);
  return (u16)(r >> 16);
}
__device__ __forceinline__ float bf2f(u16 h) {
  union { unsigned u; float f; } v; v.u = ((unsigned)h) << 16;
  return v.f;
}

__device__ __forceinline__ void gld16(const u16* g, u16* l) {
  __builtin_amdgcn_global_load_lds((const __attribute__((address_space(1))) void*)g,
                                   (__attribute__((address_space(3))) void*)l, 16, 0, 0);
}

// ---------------- fused prep: conv_x | conv_w | exp(fire_bias) table ----------------
// blocks [0,12288): x->bf16 ; [12288,12864): weight transpose ;
// [12864,13888): ebias[h][q][384] = exp(bias) zero-padded (idx = rel+64)
__global__ __launch_bounds__(256) void prep_k(const float* __restrict__ x,
                                              const float* __restrict__ Wq,
                                              const float* __restrict__ Wk,
                                              const float* __restrict__ Wv,
                                              const float* __restrict__ Wp,
                                              const float* __restrict__ w1,
                                              const float* __restrict__ b1,
                                              const float* __restrict__ w2,
                                              const float* __restrict__ b2,
                                              const float* __restrict__ cP,
                                              const float* __restrict__ LmP,
                                              u16* __restrict__ xb,
                                              u16* __restrict__ Wt,
                                              u16* __restrict__ Wtp,
                                              float* __restrict__ ebias) {
  __shared__ u16 tile[64][65];
  const int bid = blockIdx.x;
  const int tid = threadIdx.x;
  if (bid < 12288) {
    int i = bid * 256 + tid;
    xb[i] = f2bf(x[i]);
  } else if (bid < 12864) {
    int idx = bid - 12288;
    int z = idx / 144, rem = idx - z * 144;
    int k0 = (rem / 12) * 64, n0 = (rem % 12) * 64;
    const float* src = (z == 0) ? Wq : (z == 1) ? Wk : (z == 2) ? Wv : Wp;
    const int c = tid & 63, r4 = tid >> 6;
#pragma unroll
    for (int p = 0; p < 16; ++p) {
      int kk = p * 4 + r4;
      tile[kk][c] = f2bf(src[(size_t)(k0 + kk) * NC + n0 + c]);
    }
    __syncthreads();
    u16* dst = (z < 3) ? (Wt + (size_t)z * NC * NC) : Wtp;
#pragma unroll
    for (int p = 0; p < 16; ++p) {
      int nn = p * 4 + r4;
      dst[(size_t)(n0 + nn) * NC + k0 + c] = tile[c][nn];
    }
  } else {
    int q = bid - 12864;
    float c = cP[0], Lm = LmP[0];
    float thresh = fabsf(Lm * 512.0f);
    float pn = fmaxf((float)q, thresh);
    float inv_nl = 1.0f / (logf(fabsf(c * pn) + 1.0f) + 1e-6f);
    for (int idx = tid; idx < 384; idx += 256) {
      int rel = idx - 64;
      float out[NH];
      if (rel >= 0 && rel <= 256) {
        float z = logf(fabsf(c * (float)rel) + 1.0f) * inv_nl;
        float acc[NH];
#pragma unroll
        for (int hh = 0; hh < NH; ++hh) acc[hh] = b2[hh];
#pragma unroll
        for (int j = 0; j < 32; ++j) {
          float hj = fmaxf(z * w1[j] + b1[j], 0.0f);
#pragma unroll
          for (int hh = 0; hh < NH; ++hh) acc[hh] += hj * w2[j * NH + hh];
        }
#pragma unroll
        for (int hh = 0; hh < NH; ++hh) out[hh] = __expf(acc[hh]);
      } else {
#pragma unroll
        for (int hh = 0; hh < NH; ++hh) out[hh] = 0.0f;
      }
#pragma unroll
      for (int hh = 0; hh < NH; ++hh)
        ebias[((size_t)hh * NT + q) * 384 + idx] = out[hh];
    }
  }
}

// ---------------- GEMM (m97 structure): A[M][K] bf16, Bt[N][K] bf16 ----------------
template <bool F32OUT, int WR, int WC, int AI, int BJ>
__global__ __launch_bounds__(256, 4) void gemm_lds(const u16* __restrict__ A,
                                                   const u16* __restrict__ Bt,
                                                   void* __restrict__ Cv,
                                                   int M, int N, int K) {
  constexpr int BM = WR * AI * 16;
  constexpr int BN = WC * BJ * 16;
  __shared__ u16 As[BM * 32];
  __shared__ u16 Bs[BN * 32];
  const int tid = threadIdx.x;
  const int wid = tid >> 6, lane = tid & 63;
  const int wr = wid / WC, wc = wid % WC;
  const int m0 = blockIdx.x * BM, n0 = blockIdx.y * BN;
  const int lr = lane & 15, lk = (lane >> 4) << 3;
  const int srow = wid * 16 + (lane >> 2);
  const int scol = (lane & 3) * 8;
  f32x4 acc[AI][BJ] = {};
  const u16* Ag = A + (size_t)(m0 + srow) * K + scol;
  const u16* Bg = Bt + (size_t)(n0 + srow) * K + scol;
  u16* Al = &As[(wid * 16) * 32];
  u16* Bl = &Bs[(wid * 16) * 32];

  for (int k0 = 0; k0 < K; k0 += 32) {
#pragma unroll
    for (int ia = 0; ia < BM / 64; ++ia)
      gld16(Ag + (size_t)(ia * 64) * K + k0, Al + ia * 64 * 32);
#pragma unroll
    for (int ib = 0; ib < BN / 64; ++ib)
      gld16(Bg + (size_t)(ib * 64) * K + k0, Bl + ib * 64 * 32);
    __syncthreads();
    bf16x8 af[AI], bfv[BJ];
#pragma unroll
    for (int i = 0; i < AI; ++i)
      af[i] = *(const bf16x8*)&As[(wr * AI * 16 + i * 16 + lr) * 32 + lk];
#pragma unroll
    for (int j = 0; j < BJ; ++j)
      bfv[j] = *(const bf16x8*)&Bs[(wc * BJ * 16 + j * 16 + lr) * 32 + lk];
#pragma unroll
    for (int i = 0; i < AI; ++i)
#pragma unroll
      for (int j = 0; j < BJ; ++j)
        acc[i][j] = __builtin_amdgcn_mfma_f32_16x16x32_bf16(af[i], bfv[j], acc[i][j], 0, 0, 0);
    __syncthreads();
  }
  const int rbase = (lane >> 4) * 4;
#pragma unroll
  for (int i = 0; i < AI; ++i)
#pragma unroll
    for (int j = 0; j < BJ; ++j)
#pragma unroll
      for (int r = 0; r < 4; ++r) {
        size_t row = m0 + wr * AI * 16 + i * 16 + rbase + r;
        size_t col = n0 + wc * BJ * 16 + j * 16 + lr;
        if (F32OUT)
          ((float*)Cv)[row * N + col] = acc[i][j][r];
        else
          ((u16*)Cv)[row * N + col] = f2bf(acc[i][j][r]);
      }
}

// ---------------- RoPE + head split with LDS transpose for V ----------------
__global__ __launch_bounds__(256) void rope_split_k(const u16* __restrict__ qkv,
                                                    u16* __restrict__ Q,
                                                    u16* __restrict__ K,
                                                    u16* __restrict__ Vt) {
  __shared__ u16 vlds[64][65];
  const int bh = blockIdx.x;
  const int t0 = blockIdx.y * 64;
  const int b = bh / NH, h = bh - b * NH;
  const int tid = threadIdx.x;
  const int d = tid & 63;
  const int i = d & 31;
  const size_t base = ((size_t)bh << 16);
  float inv = __expf(-(float)i * (0.03125f * 9.2103403719761836f));
#pragma unroll
  for (int p = 0; p < 16; ++p) {
    int tl = p * 4 + (tid >> 6);
    int t = t0 + tl;
    size_t row = (size_t)(b * NT + t) * 2304 + h * HD;
    float ang = (float)t * inv;
    float s, c;
    __sincosf(ang, &s, &c);
    float qa = bf2f(qkv[row + i]);
    float qb = bf2f(qkv[row + i + 32]);
    float ka = bf2f(qkv[row + 768 + i]);
    float kb = bf2f(qkv[row + 768 + i + 32]);
    float qv = (d < 32) ? (qa * c - qb * s) : (qa * s + qb * c);
    float kv = (d < 32) ? (ka * c - kb * s) : (ka * s + kb * c);
    Q[base + (size_t)t * HD + d] = f2bf(qv);
    K[base + (size_t)t * HD + d] = f2bf(kv);
    vlds[tl][d] = qkv[row + 1536 + d];
  }
  __syncthreads();
#pragma unroll
  for (int p = 0; p < 16; ++p) {
    int dd = p * 4 + (tid >> 6);
    int tl = tid & 63;
    Vt[base + (size_t)dd * NT + t0 + tl] = vlds[tl][dd];
  }
}

// ---------------- windowed attention: no-max exp, pre-exp'd bias, split-K pairs ----------------
// grid (32, 48): x = q-tile pair, y = bh (mixed-length blocks interleave in dispatch).
// P = exp(s/8) * ebias[h][q][rel]  (ebias zero outside window -> masking is a multiply).
// Scores bounded (|s/8| < ~3, fp32 exp safe); softmax shift-invariance => exact same math.
__global__ __launch_bounds__(256, 4) void attn_k(const u16* __restrict__ Q,
                                                 const u16* __restrict__ K,
                                                 const u16* __restrict__ Vt,
                                                 const float* __restrict__ ebias,
                                                 u16* __restrict__ Y) {
  __shared__ __align__(16) u16 plds[4][16][72];
  __shared__ __align__(16) float mbuf[2][64][24];
  const int bh = blockIdx.y;
  const int b = bh / NH, h = bh - b * NH;
  const int wid = threadIdx.x >> 6, lane = threadIdx.x & 63;
  const int pair = wid >> 1, role = wid & 1;
  const int qt = blockIdx.x * 2 + pair;
  const int q0 = qt << 4;
  const int lr = lane & 15, lg = lane >> 4, lk = lg << 3;
  const u16* Qb = Q + ((size_t)bh << 16);
  const u16* Kb = K + ((size_t)bh << 16);
  const u16* Vb = Vt + ((size_t)bh << 16);
  const float* ebh = ebias + (size_t)h * NT * 384;

  bf16x8 aq0 = *(const bf16x8*)(Qb + (q0 + lr) * HD + lk);
  bf16x8 aq1 = *(const bf16x8*)(Qb + (q0 + lr) * HD + 32 + lk);
  f32x4 yacc[4] = {};
  float lpart[4] = {0.f, 0.f, 0.f, 0.f};
  u16(*pl)[72] = plds[wid];

  int cstart = q0 - 256;
  if (cstart < 0) cstart = 0;
  cstart &= ~63;
  const int nchunks = ((q0 + 15) - cstart) / 64 + 1;
  const int nA = nchunks >> 1;
  const int i0 = role ? nA : 0;
  const int i1 = role ? nchunks : nA;

  for (int ci = i0; ci < i1; ++ci) {
    const int c = cstart + ci * 64;
    // ebias gather first: off the critical chain (consumed only after QK MFMA)
    float eb[4][4];
#pragma unroll
    for (int kk = 0; kk < 4; ++kk) {
      const int kcol = c + kk * 16 + lr;
#pragma unroll
      for (int r = 0; r < 4; ++r) {
        int qrow = q0 + lg * 4 + r;
        int idx = qrow - kcol + 64;
        idx = idx < 0 ? 0 : (idx > 383 ? 383 : idx);  // clamps land in zero pad
        eb[kk][r] = ebh[(size_t)qrow * 384 + idx];
      }
    }
    bf16x8 bk[4][2], bv[4][2];
#pragma unroll
    for (int kk = 0; kk < 4; ++kk) {
      const u16* kp = Kb + (size_t)(c + kk * 16 + lr) * HD + lk;
      bk[kk][0] = *(const bf16x8*)kp;
      bk[kk][1] = *(const bf16x8*)(kp + 32);
    }
#pragma unroll
    for (int dt = 0; dt < 4; ++dt) {
      const u16* vp = Vb + (size_t)(dt * 16 + lr) * NT + c + lk;
      bv[dt][0] = *(const bf16x8*)vp;
      bv[dt][1] = *(const bf16x8*)(vp + 32);
    }
#pragma unroll
    for (int kk = 0; kk < 4; ++kk) {
      f32x4 t = {};
      t = __builtin_amdgcn_mfma_f32_16x16x32_bf16(aq0, bk[kk][0], t, 0, 0, 0);
      t = __builtin_amdgcn_mfma_f32_16x16x32_bf16(aq1, bk[kk][1], t, 0, 0, 0);
#pragma unroll
      for (int r = 0; r < 4; ++r) {
        float p = __expf(t[r] * 0.125f) * eb[kk][r];
        u16 pb = f2bf(p);
        pl[lg * 4 + r][kk * 16 + lr] = pb;
        lpart[r] += bf2f(pb);
      }
    }
    bf16x8 ap0 = *(const bf16x8*)&pl[lr][lk];
    bf16x8 ap1 = *(const bf16x8*)&pl[lr][32 + lk];
#pragma unroll
    for (int dt = 0; dt < 4; ++dt) {
      yacc[dt] = __builtin_amdgcn_mfma_f32_16x16x32_bf16(ap0, bv[dt][0], yacc[dt], 0, 0, 0);
      yacc[dt] = __builtin_amdgcn_mfma_f32_16x16x32_bf16(ap1, bv[dt][1], yacc[dt], 0, 0, 0);
    }
  }

  // ---- split-K merge: plain sums (no max bookkeeping) ----
  if (role == 1) {
    float* mb = &mbuf[pair][lane][0];
#pragma unroll
    for (int dt = 0; dt < 4; ++dt) *(f32x4*)(mb + dt * 4) = yacc[dt];
#pragma unroll
    for (int r = 0; r < 4; ++r) mb[16 + r] = lpart[r];
  }
  __syncthreads();
  if (role == 0) {
    const float* mb = &mbuf[pair][lane][0];
    float linv[4];
#pragma unroll
    for (int r = 0; r < 4; ++r) {
      float s = lpart[r] + mb[16 + r];
#pragma unroll
      for (int off = 1; off < 16; off <<= 1)
        s += __shfl_xor(s, off, 64);
      linv[r] = 1.0f / s;
    }
#pragma unroll
    for (int dt = 0; dt < 4; ++dt) {
      f32x4 yB = *(const f32x4*)(mb + dt * 4);
#pragma unroll
      for (int r = 0; r < 4; ++r) {
        int qrow = q0 + lg * 4 + r;
        int d = dt * 16 + lr;
        float val = (yacc[dt][r] + yB[r]) * linv[r];
        Y[(size_t)(b * NT + qrow) * NC + h * HD + d] = f2bf(val);
      }
    }
  }
}

// ---------------- workspace layout ----------------
static constexpr size_t OFF_XB = 0;                        // 4096*768*2
static constexpr size_t OFF_WT = OFF_XB + 6291456;         // 2304*768*2
static constexpr size_t OFF_WTP = OFF_WT + 3538944;        // 768*768*2
static constexpr size_t OFF_QKV = OFF_WTP + 1179648;       // 4096*2304*2
static constexpr size_t OFF_Q = OFF_QKV + 18874368;        // 48*1024*64*2
static constexpr size_t OFF_K = OFF_Q + 6291456;
static constexpr size_t OFF_VT = OFF_K + 6291456;
static constexpr size_t OFF_BIAS = OFF_VT + 6291456;       // 12*1024*384*4
static constexpr size_t OFF_Y = OFF_BIAS + 18874368;       // 4096*768*2

extern "C" void kernel_launch(void* const* d_in, const int* in_sizes, int n_in,
                              void* d_out, int out_size, void* d_ws, size_t ws_size,
                              hipStream_t stream) {
  const float* x = (const float*)d_in[0];
  const float* Wq = (const float*)d_in[1];
  const float* Wk = (const float*)d_in[2];
  const float* Wv = (const float*)d_in[3];
  const float* Wp = (const float*)d_in[4];
  const float* fw1 = (const float*)d_in[5];
  const float* fb1 = (const float*)d_in[6];
  const float* fw2 = (const float*)d_in[7];
  const float* fb2 = (const float*)d_in[8];
  const float* fc = (const float*)d_in[9];
  const float* fLm = (const float*)d_in[10];

  char* ws = (char*)d_ws;
  u16* xb = (u16*)(ws + OFF_XB);
  u16* Wt = (u16*)(ws + OFF_WT);
  u16* Wtp = (u16*)(ws + OFF_WTP);
  u16* qkv = (u16*)(ws + OFF_QKV);
  u16* Qb = (u16*)(ws + OFF_Q);
  u16* Kb = (u16*)(ws + OFF_K);
  u16* Vtb = (u16*)(ws + OFF_VT);
  float* ebiasb = (float*)(ws + OFF_BIAS);
  u16* Yb = (u16*)(ws + OFF_Y);

  prep_k<<<13888, 256, 0, stream>>>(x, Wq, Wk, Wv, Wp, fw1, fb1, fw2, fb2, fc, fLm,
                                    xb, Wt, Wtp, ebiasb);
  gemm_lds<false, 2, 2, 4, 4><<<dim3(32, 18), 256, 0, stream>>>(xb, Wt, qkv, 4096, 2304, 768);
  rope_split_k<<<dim3(48, 16), 256, 0, stream>>>(qkv, Qb, Kb, Vtb);
  attn_k<<<dim3(32, 48), 256, 0, stream>>>(Qb, Kb, Vtb, ebiasb, Yb);
  gemm_lds<true, 1, 4, 4, 2><<<dim3(64, 6), 256, 0, stream>>>(Yb, Wtp, d_out, 4096, 768, 768);
}